// Round 2
// baseline (1165.802 us; speedup 1.0000x reference)
//
#include <hip/hip_runtime.h>
#include <hip/hip_bf16.h>

#define NN 32768
#define NE 262144

typedef unsigned short u16;
typedef unsigned int   u32;

__device__ __forceinline__ float bf2f(u16 u){ return __uint_as_float(((u32)u)<<16); }
__device__ __forceinline__ u16 f2bf(float f){ __hip_bfloat16 h = __float2bfloat16(f); return *(u16*)&h; }
__device__ __forceinline__ float4 ldbf4(const u16* p){
  ushort4 u = *(const ushort4*)p;
  return make_float4(bf2f(u.x), bf2f(u.y), bf2f(u.z), bf2f(u.w));
}

// ---------------- CSR build ----------------
__global__ void k_deg(const int* __restrict__ ei, int* deg){
  int e = blockIdx.x*256 + threadIdx.x;
  if (e < NE) atomicAdd(&deg[ei[NE + e]], 1);
}

__global__ void k_scan(const int* __restrict__ deg, int* __restrict__ rowptr){
  __shared__ int sh[256];
  __shared__ int carry;
  const int t = threadIdx.x;
  if (t == 0){ carry = 0; rowptr[0] = 0; }
  __syncthreads();
  for (int c = 0; c < NN; c += 256){
    sh[t] = deg[c + t];
    __syncthreads();
    for (int o = 1; o < 256; o <<= 1){
      int u = (t >= o) ? sh[t - o] : 0;
      __syncthreads();
      sh[t] += u;
      __syncthreads();
    }
    rowptr[c + t + 1] = carry + sh[t];
    __syncthreads();
    if (t == 255) carry += sh[255];
    __syncthreads();
  }
}

__global__ void k_fill(const int* __restrict__ ei, const int* __restrict__ rowptr,
                       int* cursor, int* __restrict__ eidx){
  int e = blockIdx.x*256 + threadIdx.x;
  if (e < NE){
    int d = ei[NE + e];
    int p = atomicAdd(&cursor[d], 1);
    eidx[rowptr[d] + p] = e;
  }
}

// ---------------- EmbedConv: per-edge MLP (24->128 LN, 128->128 LN), gather-sum by dst ----------------
__global__ __launch_bounds__(256) void k_embed(
    const float* __restrict__ x, const float* __restrict__ ea, const int* __restrict__ ei,
    const int* __restrict__ rowptr, const int* __restrict__ eidx,
    const float* __restrict__ W1, const float* __restrict__ b1, const float* __restrict__ g1, const float* __restrict__ be1,
    const float* __restrict__ W2, const float* __restrict__ b2, const float* __restrict__ g2, const float* __restrict__ be2,
    float* __restrict__ h0)
{
  __shared__ float sW1[24*128];
  __shared__ u16   sW2[128*128];           // bf16 to keep LDS small
  __shared__ float sb1[128], sg1[128], sbe1[128], sb2[128], sg2[128], sbe2[128];
  __shared__ float sm[4][128];             // per-wave m buffer
  const int t = threadIdx.x;
  for (int i = t; i < 24*128;  i += 256) sW1[i] = W1[i];
  for (int i = t; i < 128*128; i += 256) sW2[i] = f2bf(W2[i]);
  if (t < 128){ sb1[t]=b1[t]; sg1[t]=g1[t]; sbe1[t]=be1[t]; sb2[t]=b2[t]; sg2[t]=g2[t]; sbe2[t]=be2[t]; }
  __syncthreads();

  const int wv = t >> 6, ln = t & 63;
  const int f0 = ln * 2;
  const int gw = blockIdx.x*4 + wv, nW = gridDim.x*4;

  for (int d = gw; d < NN; d += nW){
    const int rp = rowptr[d];
    const int dg = rowptr[d+1] - rp;
    float h_0 = 0.f, h_1 = 0.f;
    for (int j = 0; j < dg; j++){
      const int e = eidx[rp + j];
      const int s = ei[e];
      float inv = 0.f;
      if (ln < 16)      inv = x[(size_t)s*16 + ln];
      else if (ln < 24) inv = ea[(size_t)e*8 + ln - 16];

      // GEMM1: 24 -> 128 (lane owns features f0, f0+1)
      float a0 = sb1[f0], a1 = sb1[f0+1];
      #pragma unroll
      for (int i = 0; i < 24; i++){
        float vi = __shfl(inv, i, 64);
        float2 w = *(const float2*)&sW1[i*128 + f0];
        a0 += vi * w.x; a1 += vi * w.y;
      }
      a0 = fmaxf(a0, 0.f); a1 = fmaxf(a1, 0.f);
      // LN1 (wave reduce over 128 feats = 2/lane * 64 lanes)
      float s1 = a0 + a1, s2 = a0*a0 + a1*a1;
      #pragma unroll
      for (int mk = 1; mk < 64; mk <<= 1){ s1 += __shfl_xor(s1, mk, 64); s2 += __shfl_xor(s2, mk, 64); }
      float mean = s1 * (1.f/128.f);
      float rs = rsqrtf(s2*(1.f/128.f) - mean*mean + 1e-5f);
      float y0 = (a0 - mean)*rs*sg1[f0]   + sbe1[f0];
      float y1 = (a1 - mean)*rs*sg1[f0+1] + sbe1[f0+1];

      // broadcast m through per-wave LDS (same-wave RAW: waitcnt + sched_barrier fence)
      *(float2*)&sm[wv][f0] = make_float2(y0, y1);
      asm volatile("s_waitcnt lgkmcnt(0)" ::: "memory");
      __builtin_amdgcn_sched_barrier(0);

      // GEMM2: 128 -> 128
      float c0 = sb2[f0], c1 = sb2[f0+1];
      #pragma unroll
      for (int i4 = 0; i4 < 32; i4++){
        float mv[4];
        *(float4*)mv = *(const float4*)&sm[wv][i4*4];
        #pragma unroll
        for (int u = 0; u < 4; u++){
          const int i = i4*4 + u;
          u32 wp = *(const u32*)&sW2[i*128 + f0];
          float wx = __uint_as_float(wp << 16);
          float wy = __uint_as_float(wp & 0xffff0000u);
          c0 += mv[u] * wx; c1 += mv[u] * wy;
        }
      }
      c0 = fmaxf(c0, 0.f); c1 = fmaxf(c1, 0.f);
      // LN2
      s1 = c0 + c1; s2 = c0*c0 + c1*c1;
      #pragma unroll
      for (int mk = 1; mk < 64; mk <<= 1){ s1 += __shfl_xor(s1, mk, 64); s2 += __shfl_xor(s2, mk, 64); }
      mean = s1 * (1.f/128.f);
      rs = rsqrtf(s2*(1.f/128.f) - mean*mean + 1e-5f);
      h_0 += (c0 - mean)*rs*sg2[f0]   + sbe2[f0];
      h_1 += (c1 - mean)*rs*sg2[f0+1] + sbe2[f0+1];
    }
    *(float2*)&h0[(size_t)d*128 + f0] = make_float2(h_0, h_1);
  }
}

// ---------------- fused q/k/v/skip linears: [N,K] @ [K,256] x4 ----------------
template<int K>
__global__ __launch_bounds__(256) void k_qkvs(const float* __restrict__ A,
    const float* __restrict__ Wq, const float* __restrict__ bq,
    const float* __restrict__ Wk, const float* __restrict__ bk,
    const float* __restrict__ Wv, const float* __restrict__ bv,
    const float* __restrict__ Ws, const float* __restrict__ bs,
    u16* __restrict__ qo, u16* __restrict__ ko, u16* __restrict__ vo, u16* __restrict__ so)
{
  __shared__ float sA[K][16];   // transposed 16-row tile
  const int t = threadIdx.x;
  const int r0 = blockIdx.x * 16;
  const int r = t >> 4, p = t & 15;
  {
    const float* Ap = A + (size_t)(r0 + r)*K + p*(K/16);
    #pragma unroll
    for (int u = 0; u < K/16; u += 4){
      float vv[4];
      *(float4*)vv = *(const float4*)(Ap + u);
      #pragma unroll
      for (int w = 0; w < 4; w++) sA[p*(K/16) + u + w][r] = vv[w];
    }
  }
  __syncthreads();

  const int c = t;
  float aq[16] = {}, ak[16] = {}, av[16] = {}, as_[16] = {};
  #pragma unroll 2
  for (int i = 0; i < K; i++){
    float a[16];
    *(float4*)&a[0]  = *(const float4*)&sA[i][0];
    *(float4*)&a[4]  = *(const float4*)&sA[i][4];
    *(float4*)&a[8]  = *(const float4*)&sA[i][8];
    *(float4*)&a[12] = *(const float4*)&sA[i][12];
    float wq = Wq[(size_t)i*256 + c], wk = Wk[(size_t)i*256 + c];
    float wv = Wv[(size_t)i*256 + c], ws = Ws[(size_t)i*256 + c];
    #pragma unroll
    for (int rr = 0; rr < 16; rr++){
      aq[rr] += a[rr]*wq; ak[rr] += a[rr]*wk; av[rr] += a[rr]*wv; as_[rr] += a[rr]*ws;
    }
  }
  const float bqv = bq[c], bkv = bk[c], bvv = bv[c], bsv = bs[c];
  #pragma unroll
  for (int rr = 0; rr < 16; rr++){
    size_t o = (size_t)(r0 + rr)*256 + c;
    qo[o] = f2bf(aq[rr] + bqv);
    ko[o] = f2bf(ak[rr] + bkv);
    vo[o] = f2bf(av[rr] + bvv);
    so[o] = f2bf(as_[rr] + bsv);
  }
}

// ---------------- TransformerConv attention: gather by dst, online softmax; f32 output ----------------
__global__ __launch_bounds__(256) void k_attn(
    const int* __restrict__ ei, const int* __restrict__ rowptr, const int* __restrict__ eidx,
    const float* __restrict__ ea, const float* __restrict__ We,
    const u16* __restrict__ qb, const u16* __restrict__ kb, const u16* __restrict__ vb,
    const u16* __restrict__ skb, float* __restrict__ outp)
{
  __shared__ float sWe[8*256];
  const int t = threadIdx.x;
  for (int i = t; i < 2048; i += 256) sWe[i] = We[i];
  __syncthreads();

  const int wv = t >> 6, ln = t & 63;
  const int f = (ln >> 4)*64 + (ln & 15)*4;    // head = ln>>4, 4 feats/lane
  const int gw = blockIdx.x*4 + wv, nW = gridDim.x*4;

  for (int d = gw; d < NN; d += nW){
    const int rp = rowptr[d];
    const int dg = rowptr[d+1] - rp;
    float4 qv = ldbf4(qb + (size_t)d*256 + f);
    qv.x *= 0.125f; qv.y *= 0.125f; qv.z *= 0.125f; qv.w *= 0.125f;   // /sqrt(64)
    float m = -INFINITY, l = 0.f, o0 = 0, o1 = 0, o2 = 0, o3 = 0;
    for (int j = 0; j < dg; j++){
      const int e = eidx[rp + j];
      const int s = ei[e];
      float eav[8];
      *(float4*)&eav[0] = *(const float4*)&ea[(size_t)e*8];
      *(float4*)&eav[4] = *(const float4*)&ea[(size_t)e*8 + 4];
      float e0 = 0, e1 = 0, e2 = 0, e3 = 0;
      #pragma unroll
      for (int i = 0; i < 8; i++){
        float4 w = *(const float4*)&sWe[i*256 + f];
        e0 += eav[i]*w.x; e1 += eav[i]*w.y; e2 += eav[i]*w.z; e3 += eav[i]*w.w;
      }
      float4 kv = ldbf4(kb + (size_t)s*256 + f);
      float sp = qv.x*(kv.x+e0) + qv.y*(kv.y+e1) + qv.z*(kv.z+e2) + qv.w*(kv.w+e3);
      sp += __shfl_xor(sp, 1, 64); sp += __shfl_xor(sp, 2, 64);
      sp += __shfl_xor(sp, 4, 64); sp += __shfl_xor(sp, 8, 64);
      float nm = fmaxf(m, sp);
      float sc = __expf(m - nm);     // m=-inf first iter -> 0
      float pp = __expf(sp - nm);
      l = l*sc + pp;
      float4 vv = ldbf4(vb + (size_t)s*256 + f);
      o0 = o0*sc + pp*(vv.x + e0);
      o1 = o1*sc + pp*(vv.y + e1);
      o2 = o2*sc + pp*(vv.z + e2);
      o3 = o3*sc + pp*(vv.w + e3);
      m = nm;
    }
    float il = (l > 0.f) ? 1.f/l : 0.f;
    float4 sv = ldbf4(skb + (size_t)d*256 + f);
    o0 = fmaxf(o0*il + sv.x, 0.f);
    o1 = fmaxf(o1*il + sv.y, 0.f);
    o2 = fmaxf(o2*il + sv.z, 0.f);
    o3 = fmaxf(o3*il + sv.w, 0.f);
    *(float4*)(outp + (size_t)d*256 + f) = make_float4(o0, o1, o2, o3);
  }
}

extern "C" void kernel_launch(void* const* d_in, const int* in_sizes, int n_in,
                              void* d_out, int out_size, void* d_ws, size_t ws_size,
                              hipStream_t stream)
{
  (void)in_sizes; (void)n_in; (void)out_size; (void)ws_size;
  const float* x   = (const float*)d_in[0];
  const int*   ei  = (const int*)  d_in[1];
  const float* ea  = (const float*)d_in[2];
  const float* eW1 = (const float*)d_in[3];
  const float* eb1 = (const float*)d_in[4];
  const float* eg1 = (const float*)d_in[5];
  const float* ebe1= (const float*)d_in[6];
  const float* eW2 = (const float*)d_in[7];
  const float* eb2 = (const float*)d_in[8];
  const float* eg2 = (const float*)d_in[9];
  const float* ebe2= (const float*)d_in[10];

  char* ws = (char*)d_ws;
  const size_t MB = (size_t)1 << 20;
  int*   deg    = (int*)(ws);                 // 128 KB
  int*   cursor = (int*)(ws + 256*1024);      // 128 KB
  int*   rowptr = (int*)(ws + 512*1024);      // 128 KB + 4
  int*   eidx   = (int*)(ws + 1*MB);          // 1 MB
  float* h0     = (float*)(ws + 2*MB);        // 16 MB
  u16*   qb     = (u16*)(ws + 18*MB);         // 16 MB
  u16*   kb     = (u16*)(ws + 34*MB);         // 16 MB
  u16*   vb     = (u16*)(ws + 50*MB);         // 16 MB
  u16*   skb    = (u16*)(ws + 66*MB);         // 16 MB
  float* h1     = (float*)(ws + 82*MB);       // 32 MB  (total 114 MB)

  hipMemsetAsync(deg, 0, 512*1024, stream);   // zero deg + cursor

  k_deg <<<NE/256, 256, 0, stream>>>(ei, deg);
  k_scan<<<1,      256, 0, stream>>>(deg, rowptr);
  k_fill<<<NE/256, 256, 0, stream>>>(ei, rowptr, cursor, eidx);

  k_embed<<<2048, 256, 0, stream>>>(x, ea, ei, rowptr, eidx,
                                    eW1, eb1, eg1, ebe1, eW2, eb2, eg2, ebe2, h0);
  // layer 0 (din = 128)
  k_qkvs<128><<<NN/16, 256, 0, stream>>>(h0,
      (const float*)d_in[11], (const float*)d_in[12], (const float*)d_in[13], (const float*)d_in[14],
      (const float*)d_in[15], (const float*)d_in[16], (const float*)d_in[18], (const float*)d_in[19],
      qb, kb, vb, skb);
  k_attn<<<NN/4, 256, 0, stream>>>(ei, rowptr, eidx, ea, (const float*)d_in[17],
                                   qb, kb, vb, skb, h1);
  // layer 1 (din = 256)
  k_qkvs<256><<<NN/16, 256, 0, stream>>>(h1,
      (const float*)d_in[20], (const float*)d_in[21], (const float*)d_in[22], (const float*)d_in[23],
      (const float*)d_in[24], (const float*)d_in[25], (const float*)d_in[27], (const float*)d_in[28],
      qb, kb, vb, skb);
  k_attn<<<NN/4, 256, 0, stream>>>(ei, rowptr, eidx, ea, (const float*)d_in[26],
                                   qb, kb, vb, skb, (float*)d_out);
}

// Round 3
// 672.198 us; speedup vs baseline: 1.7343x; 1.7343x over previous
//
#include <hip/hip_runtime.h>
#include <hip/hip_bf16.h>

#define NN 32768
#define NE 262144

typedef unsigned short u16;
typedef unsigned int   u32;
typedef __bf16 bf16x8 __attribute__((ext_vector_type(8)));
typedef float  f32x16 __attribute__((ext_vector_type(16)));

__device__ __forceinline__ float bf2f(u16 u){ return __uint_as_float(((u32)u)<<16); }
__device__ __forceinline__ u16 f2bf(float f){ __hip_bfloat16 h = __float2bfloat16(f); return *(u16*)&h; }
__device__ __forceinline__ float4 ldbf4(const u16* p){
  ushort4 u = *(const ushort4*)p;
  return make_float4(bf2f(u.x), bf2f(u.y), bf2f(u.z), bf2f(u.w));
}

// ---------------- CSR build ----------------
__global__ void k_deg(const int* __restrict__ ei, int* deg){
  int e = blockIdx.x*256 + threadIdx.x;
  if (e < NE) atomicAdd(&deg[ei[NE + e]], 1);
}

__global__ void k_scan1(const int* __restrict__ deg, int* __restrict__ rowptr, int* __restrict__ bsum){
  const int t = threadIdx.x, b = blockIdx.x;
  const int i = b*256 + t;
  const int ln = t & 63, wv = t >> 6;
  int v = deg[i];
  #pragma unroll
  for (int d = 1; d < 64; d <<= 1){
    int u = __shfl_up(v, d, 64);
    if (ln >= d) v += u;
  }
  __shared__ int wsum[4];
  if (ln == 63) wsum[wv] = v;
  __syncthreads();
  int p = 0;
  #pragma unroll
  for (int w = 0; w < 4; w++) if (w < wv) p += wsum[w];
  v += p;
  rowptr[i + 1] = v;
  if (t == 255) bsum[b] = v;
}

__global__ void k_scan2(const int* __restrict__ bsum, int* __restrict__ boff){
  const int t = threadIdx.x;           // 128 threads
  const int ln = t & 63, wv = t >> 6;
  int own = bsum[t];
  int v = own;
  #pragma unroll
  for (int d = 1; d < 64; d <<= 1){
    int u = __shfl_up(v, d, 64);
    if (ln >= d) v += u;
  }
  __shared__ int wsum[2];
  if (ln == 63) wsum[wv] = v;
  __syncthreads();
  if (wv == 1) v += wsum[0];
  boff[t] = v - own;                   // exclusive
}

__global__ void k_scan3(int* __restrict__ rowptr, const int* __restrict__ boff){
  const int t = threadIdx.x, b = blockIdx.x;
  rowptr[1 + b*256 + t] += boff[b];
  if (b == 0 && t == 0) rowptr[0] = 0;
}

__global__ void k_fill(const int* __restrict__ ei, const int* __restrict__ rowptr,
                       int* cursor, int* __restrict__ csrc, int* __restrict__ cdst,
                       int* __restrict__ cedge){
  int e = blockIdx.x*256 + threadIdx.x;
  if (e < NE){
    int d = ei[NE + e];
    int p = rowptr[d] + atomicAdd(&cursor[d], 1);
    csrc[p]  = ei[e];
    cdst[p]  = d;
    cedge[p] = e;
  }
}

// b2p[f] = b2[f] + sum_k be1[k]*W2[k][f]
__global__ void k_b2p(const float* __restrict__ W2, const float* __restrict__ be1,
                      const float* __restrict__ b2, float* __restrict__ b2p){
  int f = threadIdx.x;   // 128
  float a = b2[f];
  for (int k = 0; k < 128; k++) a += be1[k]*W2[k*128 + f];
  b2p[f] = a;
}

// ---------------- EmbedConv via swapped-operand MFMA ----------------
// D[feat][edge] = W'^T x in  ; per block: 128 edges (4 waves x 32)
__global__ __launch_bounds__(256) void k_embed(
    const float* __restrict__ x, const float* __restrict__ ea,
    const int* __restrict__ csrc, const int* __restrict__ cdst, const int* __restrict__ cedge,
    const float* __restrict__ W1, const float* __restrict__ b1,
    const float* __restrict__ W2, const float* __restrict__ g1,
    const float* __restrict__ b2p, const float* __restrict__ g2, const float* __restrict__ be2,
    float* __restrict__ h0)
{
  __shared__ __bf16 sA1[512*8];    // [rt4][ks2][kb2][r32] 16B vecs  (W1^T + b1 row at k=24)
  __shared__ __bf16 sA2[2304*8];   // [rt4][ks9][kb2][r32]           (g1*W2^T + b2p row at k=128)
  __shared__ float  sg2[128], sbe2[128];
  const int t = threadIdx.x;

  // stage A1 (2 vecs/thread)
  #pragma unroll
  for (int ii = 0; ii < 2; ii++){
    int i = t + ii*256;
    int r = i & 31, kb = (i>>5)&1, ks = (i>>6)&1, rt = i>>7;
    int feat = rt*32 + r, k0 = ks*16 + kb*8;
    bf16x8 v;
    #pragma unroll
    for (int j = 0; j < 8; j++){
      int k = k0 + j;
      float val = (k < 24) ? W1[k*128 + feat] : ((k == 24) ? b1[feat] : 0.f);
      v[j] = (__bf16)val;
    }
    *(bf16x8*)&sA1[i*8] = v;
  }
  // stage A2 (9 vecs/thread)
  #pragma unroll
  for (int ii = 0; ii < 9; ii++){
    int i = t + ii*256;
    int r = i & 31, kb = (i>>5)&1, q = i>>6;
    int ks = q % 9, rt = q / 9;
    int feat = rt*32 + r, k0 = ks*16 + kb*8;
    bf16x8 v;
    #pragma unroll
    for (int j = 0; j < 8; j++){
      int k = k0 + j;
      float val = (k < 128) ? g1[k]*W2[k*128 + feat] : ((k == 128) ? b2p[feat] : 0.f);
      v[j] = (__bf16)val;
    }
    *(bf16x8*)&sA2[i*8] = v;
  }
  if (t < 128){ sg2[t] = g2[t]; sbe2[t] = be2[t]; }
  __syncthreads();

  const int wv = t >> 6, ln = t & 63, hi = ln >> 5, c32 = ln & 31;
  const int pos = blockIdx.x*128 + wv*32 + c32;
  const int s  = csrc[pos];
  const int e  = cedge[pos];
  const int d  = cdst[pos];

  // B1 frags in registers (gathered from global)
  bf16x8 b1f[2];
  {
    float xv[8];
    *(float4*)&xv[0] = *(const float4*)&x[(size_t)s*16 + hi*8];
    *(float4*)&xv[4] = *(const float4*)&x[(size_t)s*16 + hi*8 + 4];
    #pragma unroll
    for (int j = 0; j < 8; j++) b1f[0][j] = (__bf16)xv[j];
    float ev[8];
    *(float4*)&ev[0] = *(const float4*)&ea[(size_t)e*8];
    *(float4*)&ev[4] = *(const float4*)&ea[(size_t)e*8 + 4];
    #pragma unroll
    for (int j = 0; j < 8; j++){
      float val = hi ? ((j == 0) ? 1.f : 0.f) : ev[j];
      b1f[1][j] = (__bf16)val;
    }
  }

  // GEMM1: 8 MFMA
  f32x16 a1[4] = {};
  #pragma unroll
  for (int ks = 0; ks < 2; ks++)
    #pragma unroll
    for (int rt = 0; rt < 4; rt++){
      bf16x8 af = *(const bf16x8*)&sA1[((((rt*2 + ks)*2 + hi)*32) + c32)*8];
      a1[rt] = __builtin_amdgcn_mfma_f32_32x32x16_bf16(af, b1f[ks], a1[rt], 0, 0, 0);
    }

  // ReLU + LN1 (no affine; folded into A2)
  {
    float s1 = 0.f, s2 = 0.f;
    #pragma unroll
    for (int rt = 0; rt < 4; rt++)
      #pragma unroll
      for (int rg = 0; rg < 16; rg++){
        float v = fmaxf(a1[rt][rg], 0.f);
        a1[rt][rg] = v; s1 += v; s2 += v*v;
      }
    s1 += __shfl_xor(s1, 32, 64);
    s2 += __shfl_xor(s2, 32, 64);
    float mean = s1*(1.f/128.f);
    float rs = rsqrtf(s2*(1.f/128.f) - mean*mean + 1e-5f);
    #pragma unroll
    for (int rt = 0; rt < 4; rt++)
      #pragma unroll
      for (int rg = 0; rg < 16; rg++)
        a1[rt][rg] = (a1[rt][rg] - mean)*rs;
  }

  // GEMM2: build B2 frags in-register (lane-pair exchange), 36 MFMA
  f32x16 a2[4] = {};
  #pragma unroll
  for (int ks = 0; ks < 8; ks++){
    const int tt = ks >> 1, bb = (ks & 1)*8;
    float snd[4], rcv[4];
    #pragma unroll
    for (int j = 0; j < 4; j++)
      snd[j] = hi ? a1[tt][bb + j] : a1[tt][bb + 4 + j];
    #pragma unroll
    for (int j = 0; j < 4; j++)
      rcv[j] = __shfl_xor(snd[j], 32, 64);
    bf16x8 bf;
    #pragma unroll
    for (int j = 0; j < 4; j++){
      float lo = hi ? rcv[j] : a1[tt][bb + j];
      float hh = hi ? a1[tt][bb + 4 + j] : rcv[j];
      bf[j]     = (__bf16)lo;
      bf[4 + j] = (__bf16)hh;
    }
    #pragma unroll
    for (int rt = 0; rt < 4; rt++){
      bf16x8 af = *(const bf16x8*)&sA2[((((rt*9 + ks)*2 + hi)*32) + c32)*8];
      a2[rt] = __builtin_amdgcn_mfma_f32_32x32x16_bf16(af, bf, a2[rt], 0, 0, 0);
    }
  }
  { // ks = 8: bias row (k=128 -> 1.0 on hi=0 j=0)
    bf16x8 bf;
    #pragma unroll
    for (int j = 0; j < 8; j++)
      bf[j] = (__bf16)((!hi && j == 0) ? 1.f : 0.f);
    #pragma unroll
    for (int rt = 0; rt < 4; rt++){
      bf16x8 af = *(const bf16x8*)&sA2[((((rt*9 + 8)*2 + hi)*32) + c32)*8];
      a2[rt] = __builtin_amdgcn_mfma_f32_32x32x16_bf16(af, bf, a2[rt], 0, 0, 0);
    }
  }

  // ReLU + LN2 (normalized only; g2/be2 at scatter)
  {
    float s1 = 0.f, s2 = 0.f;
    #pragma unroll
    for (int rt = 0; rt < 4; rt++)
      #pragma unroll
      for (int rg = 0; rg < 16; rg++){
        float v = fmaxf(a2[rt][rg], 0.f);
        a2[rt][rg] = v; s1 += v; s2 += v*v;
      }
    s1 += __shfl_xor(s1, 32, 64);
    s2 += __shfl_xor(s2, 32, 64);
    float mean = s1*(1.f/128.f);
    float rs = rsqrtf(s2*(1.f/128.f) - mean*mean + 1e-5f);
    #pragma unroll
    for (int rt = 0; rt < 4; rt++)
      #pragma unroll
      for (int rg = 0; rg < 16; rg++)
        a2[rt][rg] = (a2[rt][rg] - mean)*rs;
  }

  // segmented sum across CSR-sorted lanes, then atomicAdd per segment tail
  int dprev = __shfl_up(d, 1, 32);
  int head = (c32 == 0) || (d != dprev);
  int hd = head ? c32 : 0;
  #pragma unroll
  for (int dl = 1; dl < 32; dl <<= 1){
    int o = __shfl_up(hd, dl, 32);
    if (c32 >= dl) hd = max(hd, o);
  }
  int dnext = __shfl_down(d, 1, 32);
  int tail = (c32 == 31) || (d != dnext);
  float cnt = (float)(c32 - hd + 1);

  #pragma unroll
  for (int rt = 0; rt < 4; rt++)
    #pragma unroll
    for (int rg = 0; rg < 16; rg++){
      float sv = a2[rt][rg];
      #pragma unroll
      for (int dl = 1; dl < 32; dl <<= 1){
        float o = __shfl_up(sv, dl, 32);
        if (c32 - dl >= hd) sv += o;
      }
      a2[rt][rg] = sv;
    }
  if (tail){
    #pragma unroll
    for (int rt = 0; rt < 4; rt++)
      #pragma unroll
      for (int rg = 0; rg < 16; rg++){
        int f = rt*32 + 8*(rg>>2) + 4*hi + (rg&3);
        atomicAdd(&h0[(size_t)d*128 + f], sg2[f]*a2[rt][rg] + cnt*sbe2[f]);
      }
  }
}

// ---------------- fused q/k/v/skip linears via MFMA ----------------
template<int K, bool INBF>
__global__ __launch_bounds__(256) void k_qkvs(const void* __restrict__ A_,
    const float* __restrict__ Wq, const float* __restrict__ bq,
    const float* __restrict__ Wk, const float* __restrict__ bk,
    const float* __restrict__ Wv, const float* __restrict__ bv,
    const float* __restrict__ Ws, const float* __restrict__ bs,
    u16* __restrict__ qo, u16* __restrict__ ko, u16* __restrict__ vo, u16* __restrict__ so)
{
  __shared__ __bf16 sAC[16384];   // A frags (<=32KB), reused as C staging (32KB)
  __shared__ __bf16 sB[16384];    // B chunk frags [ks4][kb2][col256] x16B = 32KB
  const int t = threadIdx.x;
  const int r0 = blockIdx.x * 64;
  const int wv = t >> 6, ln = t & 63, hi = ln >> 5, c32 = ln & 31;
  const int rt = wv & 1, ch = wv >> 1;
  const int NKS = K/16;

  // stage A tile (fragment-linear), coalesced global reads
  #pragma unroll
  for (int ii = 0; ii < 64*(K/8)/256; ii++){
    int g = t + ii*256;
    int row = g / (K/8);
    int u = g & (K/8 - 1);
    int ks = u >> 1, kb = u & 1, rtt = row >> 5, r = row & 31;
    int v = ((rtt*NKS + ks)*2 + kb)*32 + r;
    if constexpr (INBF){
      int4 dd = *(const int4*)((const u16*)A_ + (size_t)(r0 + row)*K + u*8);
      *(int4*)&sAC[v*8] = dd;
    } else {
      float av[8];
      const float* Ap = (const float*)A_ + (size_t)(r0 + row)*K + u*8;
      *(float4*)&av[0] = *(const float4*)Ap;
      *(float4*)&av[4] = *(const float4*)(Ap + 4);
      bf16x8 vec;
      #pragma unroll
      for (int j = 0; j < 8; j++) vec[j] = (__bf16)av[j];
      *(bf16x8*)&sAC[v*8] = vec;
    }
  }
  __syncthreads();

  // A frags -> registers (live across all 4 matrices)
  bf16x8 Afr[NKS];
  #pragma unroll
  for (int ks = 0; ks < NKS; ks++)
    Afr[ks] = *(const bf16x8*)&sAC[((((rt*NKS + ks)*2 + hi)*32) + c32)*8];
  __syncthreads();   // sAC now free for C staging

  const float* Wm[4] = {Wq, Wk, Wv, Ws};
  const float* bm[4] = {bq, bk, bv, bs};
  u16* om[4] = {qo, ko, vo, so};

  #pragma unroll
  for (int mat = 0; mat < 4; mat++){
    f32x16 acc[4] = {};
    #pragma unroll
    for (int c = 0; c < K/64; c++){
      __syncthreads();
      // stage B chunk [64 k][256 col] fragment-linear
      #pragma unroll
      for (int oo = 0; oo < 2; oo++){
        int oct = (t >> 6) + 4*oo;
        #pragma unroll
        for (int cr = 0; cr < 4; cr++){
          int col = (t & 63) + 64*cr;
          bf16x8 vec;
          #pragma unroll
          for (int j = 0; j < 8; j++)
            vec[j] = (__bf16)Wm[mat][(size_t)(c*64 + oct*8 + j)*256 + col];
          *(bf16x8*)&sB[(oct*256 + col)*8] = vec;
        }
      }
      __syncthreads();
      #pragma unroll
      for (int ks = 0; ks < 4; ks++)
        #pragma unroll
        for (int ct = 0; ct < 4; ct++){
          bf16x8 bfr = *(const bf16x8*)&sB[(((ks*2 + hi)*256) + ch*128 + ct*32 + c32)*8];
          acc[ct] = __builtin_amdgcn_mfma_f32_32x32x16_bf16(Afr[c*4 + ks], bfr, acc[ct], 0, 0, 0);
        }
    }
    // epilogue: bias, stage C in LDS (bf16), coalesced store
    __syncthreads();
    #pragma unroll
    for (int ct = 0; ct < 4; ct++){
      int col = ch*128 + ct*32 + c32;
      float bb = bm[mat][col];
      #pragma unroll
      for (int rg = 0; rg < 16; rg++){
        int row = rt*32 + (rg&3) + 8*(rg>>2) + 4*hi;
        sAC[row*256 + col] = (__bf16)(acc[ct][rg] + bb);
      }
    }
    __syncthreads();
    #pragma unroll
    for (int ii = 0; ii < 8; ii++){
      int v = t + ii*256;
      int4 dd = *(const int4*)&sAC[v*8];
      *(int4*)&om[mat][(size_t)(r0 + (v>>5))*256 + (v&31)*8] = dd;
    }
  }
}

// ---------------- TransformerConv attention: gather by dst, online softmax ----------------
template<bool OBF>
__global__ __launch_bounds__(256) void k_attn(
    const int* __restrict__ csrc, const int* __restrict__ rowptr, const int* __restrict__ cedge,
    const float* __restrict__ ea, const float* __restrict__ We,
    const u16* __restrict__ qb, const u16* __restrict__ kb, const u16* __restrict__ vb,
    const u16* __restrict__ skb, void* __restrict__ outp)
{
  __shared__ float sWe[8*256];
  const int t = threadIdx.x;
  for (int i = t; i < 2048; i += 256) sWe[i] = We[i];
  __syncthreads();

  const int wv = t >> 6, ln = t & 63;
  const int f = (ln >> 4)*64 + (ln & 15)*4;    // head = ln>>4, 4 feats/lane
  const int gw = blockIdx.x*4 + wv, nW = gridDim.x*4;

  for (int d = gw; d < NN; d += nW){
    const int rp = rowptr[d];
    const int dg = rowptr[d+1] - rp;
    float4 qv = ldbf4(qb + (size_t)d*256 + f);
    qv.x *= 0.125f; qv.y *= 0.125f; qv.z *= 0.125f; qv.w *= 0.125f;   // /sqrt(64)
    float m = -INFINITY, l = 0.f, o0 = 0, o1 = 0, o2 = 0, o3 = 0;
    for (int j = 0; j < dg; j++){
      const int e = cedge[rp + j];
      const int s = csrc[rp + j];
      float eav[8];
      *(float4*)&eav[0] = *(const float4*)&ea[(size_t)e*8];
      *(float4*)&eav[4] = *(const float4*)&ea[(size_t)e*8 + 4];
      float e0 = 0, e1 = 0, e2 = 0, e3 = 0;
      #pragma unroll
      for (int i = 0; i < 8; i++){
        float4 w = *(const float4*)&sWe[i*256 + f];
        e0 += eav[i]*w.x; e1 += eav[i]*w.y; e2 += eav[i]*w.z; e3 += eav[i]*w.w;
      }
      float4 kv = ldbf4(kb + (size_t)s*256 + f);
      float sp = qv.x*(kv.x+e0) + qv.y*(kv.y+e1) + qv.z*(kv.z+e2) + qv.w*(kv.w+e3);
      sp += __shfl_xor(sp, 1, 64); sp += __shfl_xor(sp, 2, 64);
      sp += __shfl_xor(sp, 4, 64); sp += __shfl_xor(sp, 8, 64);
      float nm = fmaxf(m, sp);
      float sc = __expf(m - nm);
      float pp = __expf(sp - nm);
      l = l*sc + pp;
      float4 vv = ldbf4(vb + (size_t)s*256 + f);
      o0 = o0*sc + pp*(vv.x + e0);
      o1 = o1*sc + pp*(vv.y + e1);
      o2 = o2*sc + pp*(vv.z + e2);
      o3 = o3*sc + pp*(vv.w + e3);
      m = nm;
    }
    float il = (l > 0.f) ? 1.f/l : 0.f;
    float4 sv = ldbf4(skb + (size_t)d*256 + f);
    o0 = fmaxf(o0*il + sv.x, 0.f);
    o1 = fmaxf(o1*il + sv.y, 0.f);
    o2 = fmaxf(o2*il + sv.z, 0.f);
    o3 = fmaxf(o3*il + sv.w, 0.f);
    if constexpr (OBF){
      ushort4 o; o.x = f2bf(o0); o.y = f2bf(o1); o.z = f2bf(o2); o.w = f2bf(o3);
      *(ushort4*)((u16*)outp + (size_t)d*256 + f) = o;
    } else {
      *(float4*)((float*)outp + (size_t)d*256 + f) = make_float4(o0, o1, o2, o3);
    }
  }
}

extern "C" void kernel_launch(void* const* d_in, const int* in_sizes, int n_in,
                              void* d_out, int out_size, void* d_ws, size_t ws_size,
                              hipStream_t stream)
{
  (void)in_sizes; (void)n_in; (void)out_size; (void)ws_size;
  const float* x   = (const float*)d_in[0];
  const int*   ei  = (const int*)  d_in[1];
  const float* ea  = (const float*)d_in[2];
  const float* eW1 = (const float*)d_in[3];
  const float* eb1 = (const float*)d_in[4];
  const float* eg1 = (const float*)d_in[5];
  const float* ebe1= (const float*)d_in[6];
  const float* eW2 = (const float*)d_in[7];
  const float* eb2 = (const float*)d_in[8];
  const float* eg2 = (const float*)d_in[9];
  const float* ebe2= (const float*)d_in[10];

  char* ws = (char*)d_ws;
  const size_t MB = (size_t)1 << 20;
  const size_t KB = (size_t)1 << 10;
  int*   deg    = (int*)(ws);                  // 128 KB
  int*   cursor = (int*)(ws + 128*KB);         // 128 KB
  int*   rowptr = (int*)(ws + 256*KB);         // 128 KB + 4
  int*   bsum   = (int*)(ws + 400*KB);         // 512 B
  int*   boff   = (int*)(ws + 402*KB);         // 512 B
  float* b2p    = (float*)(ws + 404*KB);       // 512 B
  int*   csrc   = (int*)(ws + 1*MB);           // 1 MB
  int*   cdst   = (int*)(ws + 2*MB);           // 1 MB
  int*   cedge  = (int*)(ws + 3*MB);           // 1 MB
  float* h0     = (float*)(ws + 4*MB);         // 16 MB
  u16*   qb     = (u16*)(ws + 20*MB);          // 16 MB
  u16*   kbuf   = (u16*)(ws + 36*MB);          // 16 MB
  u16*   vbuf   = (u16*)(ws + 52*MB);          // 16 MB
  u16*   skb    = (u16*)(ws + 68*MB);          // 16 MB
  u16*   h1     = (u16*)(ws + 84*MB);          // 16 MB (bf16)  -> total 100 MB

  hipMemsetAsync(deg, 0, 256*KB, stream);      // deg + cursor
  hipMemsetAsync(h0, 0, (size_t)NN*128*4, stream);

  k_deg  <<<NE/256, 256, 0, stream>>>(ei, deg);
  k_scan1<<<128,    256, 0, stream>>>(deg, rowptr, bsum);
  k_scan2<<<1,      128, 0, stream>>>(bsum, boff);
  k_scan3<<<128,    256, 0, stream>>>(rowptr, boff);
  k_fill <<<NE/256, 256, 0, stream>>>(ei, rowptr, cursor, csrc, cdst, cedge);
  k_b2p  <<<1,      128, 0, stream>>>(eW2, ebe1, eb2, b2p);

  k_embed<<<NE/128, 256, 0, stream>>>(x, ea, csrc, cdst, cedge,
                                      eW1, eb1, eW2, eg1, b2p, eg2, ebe2, h0);
  // layer 0 (din = 128, f32 input h0)
  k_qkvs<128,false><<<NN/64, 256, 0, stream>>>(h0,
      (const float*)d_in[11], (const float*)d_in[12], (const float*)d_in[13], (const float*)d_in[14],
      (const float*)d_in[15], (const float*)d_in[16], (const float*)d_in[18], (const float*)d_in[19],
      qb, kbuf, vbuf, skb);
  k_attn<true><<<NN/4, 256, 0, stream>>>(csrc, rowptr, cedge, ea, (const float*)d_in[17],
                                         qb, kbuf, vbuf, skb, (void*)h1);
  // layer 1 (din = 256, bf16 input h1)
  k_qkvs<256,true><<<NN/64, 256, 0, stream>>>(h1,
      (const float*)d_in[20], (const float*)d_in[21], (const float*)d_in[22], (const float*)d_in[23],
      (const float*)d_in[24], (const float*)d_in[25], (const float*)d_in[27], (const float*)d_in[28],
      qb, kbuf, vbuf, skb);
  k_attn<false><<<NN/4, 256, 0, stream>>>(csrc, rowptr, cedge, ea, (const float*)d_in[26],
                                          qb, kbuf, vbuf, skb, d_out);
}

// Round 4
// 477.668 us; speedup vs baseline: 2.4406x; 1.4072x over previous
//
#include <hip/hip_runtime.h>
#include <hip/hip_bf16.h>

#define NN 32768
#define NE 262144

typedef unsigned short u16;
typedef unsigned int   u32;
typedef __bf16 bf16x8 __attribute__((ext_vector_type(8)));
typedef float  f32x16 __attribute__((ext_vector_type(16)));

__device__ __forceinline__ float bf2f(u16 u){ return __uint_as_float(((u32)u)<<16); }
__device__ __forceinline__ u16 f2bf(float f){ __hip_bfloat16 h = __float2bfloat16(f); return *(u16*)&h; }
__device__ __forceinline__ float4 ldbf4(const u16* p){
  ushort4 u = *(const ushort4*)p;
  return make_float4(bf2f(u.x), bf2f(u.y), bf2f(u.z), bf2f(u.w));
}
__device__ __forceinline__ void gload16(const void* g, void* l){
  __builtin_amdgcn_global_load_lds(
      (const __attribute__((address_space(1))) void*)g,
      (__attribute__((address_space(3))) void*)l, 16, 0, 0);
}

// ---------------- CSR build ----------------
__global__ void k_deg(const int* __restrict__ ei, int* deg){
  int e = blockIdx.x*256 + threadIdx.x;
  if (e < NE) atomicAdd(&deg[ei[NE + e]], 1);
}

__global__ void k_scan1(const int* __restrict__ deg, int* __restrict__ rowptr, int* __restrict__ bsum){
  const int t = threadIdx.x, b = blockIdx.x;
  const int i = b*256 + t;
  const int ln = t & 63, wv = t >> 6;
  int v = deg[i];
  #pragma unroll
  for (int d = 1; d < 64; d <<= 1){
    int u = __shfl_up(v, d, 64);
    if (ln >= d) v += u;
  }
  __shared__ int wsum[4];
  if (ln == 63) wsum[wv] = v;
  __syncthreads();
  int p = 0;
  #pragma unroll
  for (int w = 0; w < 4; w++) if (w < wv) p += wsum[w];
  v += p;
  rowptr[i + 1] = v;
  if (t == 255) bsum[b] = v;
}

__global__ void k_scan2(const int* __restrict__ bsum, int* __restrict__ boff){
  const int t = threadIdx.x;           // 128 threads
  const int ln = t & 63, wv = t >> 6;
  int own = bsum[t];
  int v = own;
  #pragma unroll
  for (int d = 1; d < 64; d <<= 1){
    int u = __shfl_up(v, d, 64);
    if (ln >= d) v += u;
  }
  __shared__ int wsum[2];
  if (ln == 63) wsum[wv] = v;
  __syncthreads();
  if (wv == 1) v += wsum[0];
  boff[t] = v - own;                   // exclusive
}

__global__ void k_scan3(int* __restrict__ rowptr, const int* __restrict__ boff){
  const int t = threadIdx.x, b = blockIdx.x;
  rowptr[1 + b*256 + t] += boff[b];
  if (b == 0 && t == 0) rowptr[0] = 0;
}

__global__ void k_fill(const int* __restrict__ ei, const int* __restrict__ rowptr,
                       int* cursor, int* __restrict__ csrc, int* __restrict__ cdst,
                       int* __restrict__ cedge){
  int e = blockIdx.x*256 + threadIdx.x;
  if (e < NE){
    int d = ei[NE + e];
    int p = rowptr[d] + atomicAdd(&cursor[d], 1);
    csrc[p]  = ei[e];
    cdst[p]  = d;
    cedge[p] = e;
  }
}

// b2p[f] = b2[f] + sum_k be1[k]*W2[k][f]
__global__ void k_b2p(const float* __restrict__ W2, const float* __restrict__ be1,
                      const float* __restrict__ b2, float* __restrict__ b2p){
  int f = threadIdx.x;   // 128
  float a = b2[f];
  for (int k = 0; k < 128; k++) a += be1[k]*W2[k*128 + f];
  b2p[f] = a;
}

// ---------------- weight prep: 8 matrices -> bf16 fragment-linear concat, biases concat ----------------
struct WPtrs { const float* w[8]; const float* b[8]; };

__global__ void k_wprep(WPtrs wp, __bf16* __restrict__ W0cat, __bf16* __restrict__ W1cat,
                        float* __restrict__ bcat0, float* __restrict__ bcat1){
  int gid = blockIdx.x*256 + threadIdx.x;
  if (gid < 16384){                       // layer0: 4 mats x 4096 vecs (K=128)
    int mat = gid >> 12, v = gid & 4095;
    int colm = v & 255, q = v >> 8;       // q = ksg*2+hi, ksg<8
    int k0 = (q>>1)*16 + (q&1)*8;
    const float* W = wp.w[mat];
    bf16x8 vec;
    #pragma unroll
    for (int j = 0; j < 8; j++) vec[j] = (__bf16)W[(size_t)(k0+j)*256 + colm];
    *(bf16x8*)&W0cat[((size_t)q*1024 + mat*256 + colm)*8] = vec;
  } else if (gid < 49152){                // layer1: 4 mats x 8192 vecs (K=256)
    int g = gid - 16384;
    int mat = g >> 13, v = g & 8191;
    int colm = v & 255, q = v >> 8;       // q<32
    int k0 = (q>>1)*16 + (q&1)*8;
    const float* W = wp.w[4+mat];
    bf16x8 vec;
    #pragma unroll
    for (int j = 0; j < 8; j++) vec[j] = (__bf16)W[(size_t)(k0+j)*256 + colm];
    *(bf16x8*)&W1cat[((size_t)q*1024 + mat*256 + colm)*8] = vec;
  } else if (gid < 51200){
    int g = gid - 49152;
    if (g < 1024) bcat0[g] = wp.b[g>>8][g&255];
    else { int h = g-1024; bcat1[h] = wp.b[4 + (h>>8)][h&255]; }
  }
}

// h0 f32 -> bf16
__global__ void k_cvt(const float* __restrict__ h, u16* __restrict__ hb){
  int v = blockIdx.x*256 + threadIdx.x;   // x8 elems
  float a[8];
  *(float4*)&a[0] = *(const float4*)&h[(size_t)v*8];
  *(float4*)&a[4] = *(const float4*)&h[(size_t)v*8 + 4];
  bf16x8 o;
  #pragma unroll
  for (int j = 0; j < 8; j++) o[j] = (__bf16)a[j];
  *(bf16x8*)((__bf16*)hb + (size_t)v*8) = o;
}

// ---------------- EmbedConv via swapped-operand MFMA ----------------
__global__ __launch_bounds__(256) void k_embed(
    const float* __restrict__ x, const float* __restrict__ ea,
    const int* __restrict__ csrc, const int* __restrict__ cdst, const int* __restrict__ cedge,
    const float* __restrict__ W1, const float* __restrict__ b1,
    const float* __restrict__ W2, const float* __restrict__ g1,
    const float* __restrict__ b2p, const float* __restrict__ g2, const float* __restrict__ be2,
    float* __restrict__ h0)
{
  __shared__ __bf16 sA1[512*8];
  __shared__ __bf16 sA2[2304*8];
  __shared__ float  sg2[128], sbe2[128];
  const int t = threadIdx.x;

  #pragma unroll
  for (int ii = 0; ii < 2; ii++){
    int i = t + ii*256;
    int r = i & 31, kb = (i>>5)&1, ks = (i>>6)&1, rt = i>>7;
    int feat = rt*32 + r, k0 = ks*16 + kb*8;
    bf16x8 v;
    #pragma unroll
    for (int j = 0; j < 8; j++){
      int k = k0 + j;
      float val = (k < 24) ? W1[k*128 + feat] : ((k == 24) ? b1[feat] : 0.f);
      v[j] = (__bf16)val;
    }
    *(bf16x8*)&sA1[i*8] = v;
  }
  #pragma unroll
  for (int ii = 0; ii < 9; ii++){
    int i = t + ii*256;
    int r = i & 31, kb = (i>>5)&1, q = i>>6;
    int ks = q % 9, rt = q / 9;
    int feat = rt*32 + r, k0 = ks*16 + kb*8;
    bf16x8 v;
    #pragma unroll
    for (int j = 0; j < 8; j++){
      int k = k0 + j;
      float val = (k < 128) ? g1[k]*W2[k*128 + feat] : ((k == 128) ? b2p[feat] : 0.f);
      v[j] = (__bf16)val;
    }
    *(bf16x8*)&sA2[i*8] = v;
  }
  if (t < 128){ sg2[t] = g2[t]; sbe2[t] = be2[t]; }
  __syncthreads();

  const int wv = t >> 6, ln = t & 63, hi = ln >> 5, c32 = ln & 31;
  const int pos = blockIdx.x*128 + wv*32 + c32;
  const int s  = csrc[pos];
  const int e  = cedge[pos];
  const int d  = cdst[pos];

  bf16x8 b1f[2];
  {
    float xv[8];
    *(float4*)&xv[0] = *(const float4*)&x[(size_t)s*16 + hi*8];
    *(float4*)&xv[4] = *(const float4*)&x[(size_t)s*16 + hi*8 + 4];
    #pragma unroll
    for (int j = 0; j < 8; j++) b1f[0][j] = (__bf16)xv[j];
    float ev[8];
    *(float4*)&ev[0] = *(const float4*)&ea[(size_t)e*8];
    *(float4*)&ev[4] = *(const float4*)&ea[(size_t)e*8 + 4];
    #pragma unroll
    for (int j = 0; j < 8; j++){
      float val = hi ? ((j == 0) ? 1.f : 0.f) : ev[j];
      b1f[1][j] = (__bf16)val;
    }
  }

  f32x16 a1[4] = {};
  #pragma unroll
  for (int ks = 0; ks < 2; ks++)
    #pragma unroll
    for (int rt = 0; rt < 4; rt++){
      bf16x8 af = *(const bf16x8*)&sA1[((((rt*2 + ks)*2 + hi)*32) + c32)*8];
      a1[rt] = __builtin_amdgcn_mfma_f32_32x32x16_bf16(af, b1f[ks], a1[rt], 0, 0, 0);
    }

  {
    float s1 = 0.f, s2 = 0.f;
    #pragma unroll
    for (int rt = 0; rt < 4; rt++)
      #pragma unroll
      for (int rg = 0; rg < 16; rg++){
        float v = fmaxf(a1[rt][rg], 0.f);
        a1[rt][rg] = v; s1 += v; s2 += v*v;
      }
    s1 += __shfl_xor(s1, 32, 64);
    s2 += __shfl_xor(s2, 32, 64);
    float mean = s1*(1.f/128.f);
    float rs = rsqrtf(s2*(1.f/128.f) - mean*mean + 1e-5f);
    #pragma unroll
    for (int rt = 0; rt < 4; rt++)
      #pragma unroll
      for (int rg = 0; rg < 16; rg++)
        a1[rt][rg] = (a1[rt][rg] - mean)*rs;
  }

  f32x16 a2[4] = {};
  #pragma unroll
  for (int ks = 0; ks < 8; ks++){
    const int tt = ks >> 1, bb = (ks & 1)*8;
    float snd[4], rcv[4];
    #pragma unroll
    for (int j = 0; j < 4; j++)
      snd[j] = hi ? a1[tt][bb + j] : a1[tt][bb + 4 + j];
    #pragma unroll
    for (int j = 0; j < 4; j++)
      rcv[j] = __shfl_xor(snd[j], 32, 64);
    bf16x8 bf;
    #pragma unroll
    for (int j = 0; j < 4; j++){
      float lo = hi ? rcv[j] : a1[tt][bb + j];
      float hh = hi ? a1[tt][bb + 4 + j] : rcv[j];
      bf[j]     = (__bf16)lo;
      bf[4 + j] = (__bf16)hh;
    }
    #pragma unroll
    for (int rt = 0; rt < 4; rt++){
      bf16x8 af = *(const bf16x8*)&sA2[((((rt*9 + ks)*2 + hi)*32) + c32)*8];
      a2[rt] = __builtin_amdgcn_mfma_f32_32x32x16_bf16(af, bf, a2[rt], 0, 0, 0);
    }
  }
  {
    bf16x8 bf;
    #pragma unroll
    for (int j = 0; j < 8; j++)
      bf[j] = (__bf16)((!hi && j == 0) ? 1.f : 0.f);
    #pragma unroll
    for (int rt = 0; rt < 4; rt++){
      bf16x8 af = *(const bf16x8*)&sA2[((((rt*9 + 8)*2 + hi)*32) + c32)*8];
      a2[rt] = __builtin_amdgcn_mfma_f32_32x32x16_bf16(af, bf, a2[rt], 0, 0, 0);
    }
  }

  {
    float s1 = 0.f, s2 = 0.f;
    #pragma unroll
    for (int rt = 0; rt < 4; rt++)
      #pragma unroll
      for (int rg = 0; rg < 16; rg++){
        float v = fmaxf(a2[rt][rg], 0.f);
        a2[rt][rg] = v; s1 += v; s2 += v*v;
      }
    s1 += __shfl_xor(s1, 32, 64);
    s2 += __shfl_xor(s2, 32, 64);
    float mean = s1*(1.f/128.f);
    float rs = rsqrtf(s2*(1.f/128.f) - mean*mean + 1e-5f);
    #pragma unroll
    for (int rt = 0; rt < 4; rt++)
      #pragma unroll
      for (int rg = 0; rg < 16; rg++)
        a2[rt][rg] = (a2[rt][rg] - mean)*rs;
  }

  int dprev = __shfl_up(d, 1, 32);
  int head = (c32 == 0) || (d != dprev);
  int hd = head ? c32 : 0;
  #pragma unroll
  for (int dl = 1; dl < 32; dl <<= 1){
    int o = __shfl_up(hd, dl, 32);
    if (c32 >= dl) hd = max(hd, o);
  }
  int dnext = __shfl_down(d, 1, 32);
  int tail = (c32 == 31) || (d != dnext);
  float cnt = (float)(c32 - hd + 1);

  #pragma unroll
  for (int rt = 0; rt < 4; rt++)
    #pragma unroll
    for (int rg = 0; rg < 16; rg++){
      float sv = a2[rt][rg];
      #pragma unroll
      for (int dl = 1; dl < 32; dl <<= 1){
        float o = __shfl_up(sv, dl, 32);
        if (c32 - dl >= hd) sv += o;
      }
      a2[rt][rg] = sv;
    }
  if (tail){
    #pragma unroll
    for (int rt = 0; rt < 4; rt++)
      #pragma unroll
      for (int rg = 0; rg < 16; rg++){
        int f = rt*32 + 8*(rg>>2) + 4*hi + (rg&3);
        atomicAdd(&h0[(size_t)d*128 + f], sg2[f]*a2[rt][rg] + cnt*sbe2[f]);
      }
  }
}

// ---------------- qkvs GEMM v2: [N,K]bf16 @ Wcat[K,1024]bf16, 128x128 tiles, global_load_lds ----------------
template<int K>
__global__ __launch_bounds__(256) void k_qkvs2(const u16* __restrict__ A,
    const __bf16* __restrict__ Wcat, const float* __restrict__ bcat,
    u16* __restrict__ qo, u16* __restrict__ ko, u16* __restrict__ vo, u16* __restrict__ so)
{
  __shared__ alignas(16) __bf16 sA[1024*8];   // 16 KB: [rt4][ks4][hi2][r32] x8
  __shared__ alignas(16) __bf16 sB[1024*8];   // 16 KB: [ks4][hi2][col128] x8
  const int t = threadIdx.x;
  // XCD-bijective swizzle: 2048 blocks, 8 XCDs -> each XCD gets 32 consecutive row-tiles
  const int swz = (blockIdx.x & 7)*256 + (blockIdx.x >> 3);
  const int r0 = (swz >> 3)*128, c0 = (swz & 7)*128;
  const int wv = t >> 6, ln = t & 63, hi = ln >> 5, c32 = ln & 31;
  const int wr = wv >> 1, wc = wv & 1;

  f32x16 acc[2][2] = {};
  for (int kc = 0; kc < K/64; kc++){
    __syncthreads();
    #pragma unroll
    for (int ii = 0; ii < 4; ii++){          // A chunk: 1024 vecs of 16B
      int v = ii*256 + wv*64 + ln;
      int r = v & 31, hh = (v>>5)&1, ks = (v>>6)&3, rt = v>>8;
      const u16* src = A + (size_t)(r0 + rt*32 + r)*K + kc*64 + ks*16 + hh*8;
      gload16(src, &sA[(size_t)(ii*256 + wv*64)*8]);
    }
    #pragma unroll
    for (int ii = 0; ii < 4; ii++){          // B chunk: 1024 vecs
      int v = ii*256 + wv*64 + ln;
      int col = v & 127, q = v >> 7;
      const __bf16* src = Wcat + ((size_t)(kc*8 + q)*1024 + c0 + col)*8;
      gload16(src, &sB[(size_t)(ii*256 + wv*64)*8]);
    }
    asm volatile("s_waitcnt vmcnt(0)" ::: "memory");
    __syncthreads();
    #pragma unroll
    for (int ks = 0; ks < 4; ks++){
      bf16x8 af0 = *(const bf16x8*)&sA[((((wr*2+0)*4 + ks)*2 + hi)*32 + c32)*8];
      bf16x8 af1 = *(const bf16x8*)&sA[((((wr*2+1)*4 + ks)*2 + hi)*32 + c32)*8];
      bf16x8 bf0 = *(const bf16x8*)&sB[(((ks*2 + hi)*128) + wc*64 + c32)*8];
      bf16x8 bf1 = *(const bf16x8*)&sB[(((ks*2 + hi)*128) + wc*64 + 32 + c32)*8];
      acc[0][0] = __builtin_amdgcn_mfma_f32_32x32x16_bf16(af0, bf0, acc[0][0], 0, 0, 0);
      acc[0][1] = __builtin_amdgcn_mfma_f32_32x32x16_bf16(af0, bf1, acc[0][1], 0, 0, 0);
      acc[1][0] = __builtin_amdgcn_mfma_f32_32x32x16_bf16(af1, bf0, acc[1][0], 0, 0, 0);
      acc[1][1] = __builtin_amdgcn_mfma_f32_32x32x16_bf16(af1, bf1, acc[1][1], 0, 0, 0);
    }
  }

  u16* om = (c0 < 256) ? qo : (c0 < 512) ? ko : (c0 < 768) ? vo : so;
  const int cb = c0 & 255;
  #pragma unroll
  for (int ci = 0; ci < 2; ci++){
    int colm = cb + wc*64 + ci*32 + c32;
    float bb = bcat[c0 + wc*64 + ci*32 + c32];
    #pragma unroll
    for (int ri = 0; ri < 2; ri++){
      #pragma unroll
      for (int rg = 0; rg < 16; rg++){
        int row = r0 + (wr*2 + ri)*32 + (rg&3) + 8*(rg>>2) + 4*hi;
        om[(size_t)row*256 + colm] = f2bf(acc[ri][ci][rg] + bb);
      }
    }
  }
}

// ---------------- TransformerConv attention: gather by dst, online softmax ----------------
template<bool OBF>
__global__ __launch_bounds__(256) void k_attn(
    const int* __restrict__ csrc, const int* __restrict__ rowptr, const int* __restrict__ cedge,
    const float* __restrict__ ea, const float* __restrict__ We,
    const u16* __restrict__ qb, const u16* __restrict__ kb, const u16* __restrict__ vb,
    const u16* __restrict__ skb, void* __restrict__ outp)
{
  __shared__ float sWe[8*256];
  const int t = threadIdx.x;
  for (int i = t; i < 2048; i += 256) sWe[i] = We[i];
  __syncthreads();

  const int wv = t >> 6, ln = t & 63;
  const int f = (ln >> 4)*64 + (ln & 15)*4;
  const int gw = blockIdx.x*4 + wv, nW = gridDim.x*4;

  for (int d = gw; d < NN; d += nW){
    const int rp = rowptr[d];
    const int dg = rowptr[d+1] - rp;
    float4 qv = ldbf4(qb + (size_t)d*256 + f);
    qv.x *= 0.125f; qv.y *= 0.125f; qv.z *= 0.125f; qv.w *= 0.125f;
    float m = -INFINITY, l = 0.f, o0 = 0, o1 = 0, o2 = 0, o3 = 0;
    for (int j = 0; j < dg; j++){
      const int e = cedge[rp + j];
      const int s = csrc[rp + j];
      float eav[8];
      *(float4*)&eav[0] = *(const float4*)&ea[(size_t)e*8];
      *(float4*)&eav[4] = *(const float4*)&ea[(size_t)e*8 + 4];
      float e0 = 0, e1 = 0, e2 = 0, e3 = 0;
      #pragma unroll
      for (int i = 0; i < 8; i++){
        float4 w = *(const float4*)&sWe[i*256 + f];
        e0 += eav[i]*w.x; e1 += eav[i]*w.y; e2 += eav[i]*w.z; e3 += eav[i]*w.w;
      }
      float4 kv = ldbf4(kb + (size_t)s*256 + f);
      float sp = qv.x*(kv.x+e0) + qv.y*(kv.y+e1) + qv.z*(kv.z+e2) + qv.w*(kv.w+e3);
      sp += __shfl_xor(sp, 1, 64); sp += __shfl_xor(sp, 2, 64);
      sp += __shfl_xor(sp, 4, 64); sp += __shfl_xor(sp, 8, 64);
      float nm = fmaxf(m, sp);
      float sc = __expf(m - nm);
      float pp = __expf(sp - nm);
      l = l*sc + pp;
      float4 vv = ldbf4(vb + (size_t)s*256 + f);
      o0 = o0*sc + pp*(vv.x + e0);
      o1 = o1*sc + pp*(vv.y + e1);
      o2 = o2*sc + pp*(vv.z + e2);
      o3 = o3*sc + pp*(vv.w + e3);
      m = nm;
    }
    float il = (l > 0.f) ? 1.f/l : 0.f;
    float4 sv = ldbf4(skb + (size_t)d*256 + f);
    o0 = fmaxf(o0*il + sv.x, 0.f);
    o1 = fmaxf(o1*il + sv.y, 0.f);
    o2 = fmaxf(o2*il + sv.z, 0.f);
    o3 = fmaxf(o3*il + sv.w, 0.f);
    if constexpr (OBF){
      ushort4 o; o.x = f2bf(o0); o.y = f2bf(o1); o.z = f2bf(o2); o.w = f2bf(o3);
      *(ushort4*)((u16*)outp + (size_t)d*256 + f) = o;
    } else {
      *(float4*)((float*)outp + (size_t)d*256 + f) = make_float4(o0, o1, o2, o3);
    }
  }
}

extern "C" void kernel_launch(void* const* d_in, const int* in_sizes, int n_in,
                              void* d_out, int out_size, void* d_ws, size_t ws_size,
                              hipStream_t stream)
{
  (void)in_sizes; (void)n_in; (void)out_size; (void)ws_size;
  const float* x   = (const float*)d_in[0];
  const int*   ei  = (const int*)  d_in[1];
  const float* ea  = (const float*)d_in[2];
  const float* eW1 = (const float*)d_in[3];
  const float* eb1 = (const float*)d_in[4];
  const float* eg1 = (const float*)d_in[5];
  const float* ebe1= (const float*)d_in[6];
  const float* eW2 = (const float*)d_in[7];
  const float* eb2 = (const float*)d_in[8];
  const float* eg2 = (const float*)d_in[9];
  const float* ebe2= (const float*)d_in[10];

  char* ws = (char*)d_ws;
  const size_t MB = (size_t)1 << 20;
  const size_t KB = (size_t)1 << 10;
  int*   deg    = (int*)(ws);                  // 128 KB
  int*   cursor = (int*)(ws + 128*KB);         // 128 KB
  int*   rowptr = (int*)(ws + 256*KB);         // 128 KB + 4
  int*   bsum   = (int*)(ws + 400*KB);
  int*   boff   = (int*)(ws + 402*KB);
  float* b2p    = (float*)(ws + 404*KB);
  int*   csrc   = (int*)(ws + 1*MB);           // 1 MB
  int*   cdst   = (int*)(ws + 2*MB);           // 1 MB
  int*   cedge  = (int*)(ws + 3*MB);           // 1 MB
  float* h0     = (float*)(ws + 4*MB);         // 16 MB
  u16*   qb     = (u16*)(ws + 20*MB);          // 16 MB
  u16*   kbuf   = (u16*)(ws + 36*MB);          // 16 MB
  u16*   vbuf   = (u16*)(ws + 52*MB);          // 16 MB
  u16*   skb    = (u16*)(ws + 68*MB);          // 16 MB
  u16*   h1     = (u16*)(ws + 84*MB);          // 16 MB (bf16)
  u16*   h0b    = (u16*)(ws + 100*MB);         // 8 MB (bf16)
  __bf16* W0cat = (__bf16*)(ws + 108*MB);      // 256 KB
  __bf16* W1cat = (__bf16*)(ws + 109*MB);      // 512 KB
  float* bcat0  = (float*)(ws + 110*MB);       // 4 KB
  float* bcat1  = (float*)(ws + 110*MB + 64*KB); // 4 KB  -> total ~111 MB

  hipMemsetAsync(deg, 0, 256*KB, stream);      // deg + cursor
  hipMemsetAsync(h0, 0, (size_t)NN*128*4, stream);

  k_deg  <<<NE/256, 256, 0, stream>>>(ei, deg);
  k_scan1<<<128,    256, 0, stream>>>(deg, rowptr, bsum);
  k_scan2<<<1,      128, 0, stream>>>(bsum, boff);
  k_scan3<<<128,    256, 0, stream>>>(rowptr, boff);
  k_fill <<<NE/256, 256, 0, stream>>>(ei, rowptr, cursor, csrc, cdst, cedge);
  k_b2p  <<<1,      128, 0, stream>>>(eW2, ebe1, eb2, b2p);

  WPtrs wp;
  wp.w[0] = (const float*)d_in[11]; wp.b[0] = (const float*)d_in[12];   // l0 Wq bq
  wp.w[1] = (const float*)d_in[13]; wp.b[1] = (const float*)d_in[14];   // l0 Wk bk
  wp.w[2] = (const float*)d_in[15]; wp.b[2] = (const float*)d_in[16];   // l0 Wv bv
  wp.w[3] = (const float*)d_in[18]; wp.b[3] = (const float*)d_in[19];   // l0 Ws bs
  wp.w[4] = (const float*)d_in[20]; wp.b[4] = (const float*)d_in[21];   // l1 Wq bq
  wp.w[5] = (const float*)d_in[22]; wp.b[5] = (const float*)d_in[23];   // l1 Wk bk
  wp.w[6] = (const float*)d_in[24]; wp.b[6] = (const float*)d_in[25];   // l1 Wv bv
  wp.w[7] = (const float*)d_in[27]; wp.b[7] = (const float*)d_in[28];   // l1 Ws bs
  k_wprep<<<200, 256, 0, stream>>>(wp, W0cat, W1cat, bcat0, bcat1);

  k_embed<<<NE/128, 256, 0, stream>>>(x, ea, csrc, cdst, cedge,
                                      eW1, eb1, eW2, eg1, b2p, eg2, ebe2, h0);
  k_cvt<<<2048, 256, 0, stream>>>(h0, h0b);

  // layer 0 (K = 128)
  k_qkvs2<128><<<2048, 256, 0, stream>>>(h0b, W0cat, bcat0, qb, kbuf, vbuf, skb);
  k_attn<true><<<NN/4, 256, 0, stream>>>(csrc, rowptr, cedge, ea, (const float*)d_in[17],
                                         qb, kbuf, vbuf, skb, (void*)h1);
  // layer 1 (K = 256)
  k_qkvs2<256><<<2048, 256, 0, stream>>>(h1, W1cat, bcat1, qb, kbuf, vbuf, skb);
  k_attn<false><<<NN/4, 256, 0, stream>>>(csrc, rowptr, cedge, ea, (const float*)d_in[26],
                                          qb, kbuf, vbuf, skb, d_out);
}